// Round 12
// baseline (156.710 us; speedup 1.0000x reference)
//
#include <hip/hip_runtime.h>
#include <hip/hip_bf16.h>

// Problem constants
#define NB   8
#define CCH  64
#define CR8  8
#define NPX  2304           // 48*48
#define BCN  (NB*CCH*NPX)   // 1179648
#define LOG2E 1.4426950408889634f

typedef short  short8   __attribute__((ext_vector_type(8)));
typedef unsigned short ushort8t __attribute__((ext_vector_type(8)));
typedef float  float4t  __attribute__((ext_vector_type(4)));
typedef float  float16t __attribute__((ext_vector_type(16)));

// native v_exp_f32 (1 inst; ~1 ulp; valid for our |x| < ~50 range).
static __device__ __forceinline__ float fexp2(float x) {
    return __builtin_amdgcn_exp2f(x);
}
// round-half-up bf16 from f32: (u + 0x8000) >> 16  (<=1 ulp vs RNE)
static __device__ __forceinline__ unsigned short bf16r(float f) {
    return (unsigned short)((__float_as_uint(f) + 0x8000u) >> 16);
}
// pack two f32 -> two bf16 in one dword: [hi16(hi) : hi16(lo)], 3 VALU inst
static __device__ __forceinline__ unsigned int pack_bf16(float lo, float hi) {
    const unsigned int ul = __float_as_uint(lo) + 0x8000u;
    const unsigned int uh = __float_as_uint(hi) + 0x8000u;
    return __builtin_amdgcn_perm(uh, ul, 0x07060302u);
}
// 8 floats -> short8 bf16 fragment (4 perms)
static __device__ __forceinline__ short8 pack8(const float* f) {
    union { unsigned int u[4]; short8 s; } r;
    #pragma unroll
    for (int j = 0; j < 4; j++) r.u[j] = pack_bf16(f[2*j], f[2*j+1]);
    return r.s;
}

// Build the two PV B-fragments (K=16 chunks kp=0,1) for one 32x32 S-MFMA
// output, entirely in registers. S output: lane (j=l&31, hs=l>>5) reg r holds
// S[row=(r&3)+8*(r>>2)+4*hs][j]. After exp2+pack, d[q][m] holds rows
// (8q+4hs+2m, +2m+1). B-frag for chunk kp needs lane (j,h) to hold rows
// 16kp+8h+0..7 at k-octet h. v_permlane32_swap_b32 (dst.row1 <-> src.row0):
//   x' = {x.lo, y.lo}, y' = {x.hi, y.hi}
// so swap(d[2kp][m], d[2kp+1][m]) yields frag words (m, 2+m) for ALL lanes.
// [verified R1/R2/R5/R6/R8/R9/R11]
static __device__ __forceinline__ void build_bfrag(const float16t sc, short8* bf) {
    unsigned int d[4][2];
    #pragma unroll
    for (int q = 0; q < 4; q++) {
        #pragma unroll
        for (int m = 0; m < 2; m++)
            d[q][m] = pack_bf16(fexp2(sc[4*q + 2*m]), fexp2(sc[4*q + 2*m + 1]));
    }
    #pragma unroll
    for (int kp = 0; kp < 2; kp++) {
        union { unsigned int u[4]; short8 s; } r;
        #pragma unroll
        for (int m = 0; m < 2; m++) {
            unsigned int x = d[2*kp][m];
            unsigned int y = d[2*kp + 1][m];
            asm("v_permlane32_swap_b32 %0, %1" : "+v"(x), "+v"(y));
            r.u[m]     = x;
            r.u[2 + m] = y;
        }
        bf[kp] = r.s;
    }
}

// Workspace layout (float offsets)
// qb/kb: bf16 [b][i][16] rows. qb: c 0..7 = q*log2e, slots 8/9 get
// -log2(D_i) hi/lo AFTER stats; kb: c 0..7 = k, slots 8/9 = 1.0.
// The S-MFMA in out_kernel then yields log2(P_normalized) directly.
#define WS_QB1 0
#define WS_KB1 (WS_QB1 + 147456)
#define WS_QB2 (WS_KB1 + 147456)
#define WS_KB2 (WS_QB2 + 147456)
#define WS_V1  (WS_KB2 + 147456)        // bf16 [b][c][i], unscaled
#define WS_V2  (WS_V1 + BCN/2)

// ---------------------------------------------------------------------------
// Kernel 1: projections as MFMA GEMM. M=160 rows (qk1,qk2,v1,v2), N=px, K=64.
// grid (72 pxtiles of 32, 8 b), block 256 = 4 independent waves, NO LDS,
// NO barriers. Also writes out = x residual-init. kb pad slots 8,9 = 1.0.
// [R2-verified verbatim]
// ---------------------------------------------------------------------------
__global__ __launch_bounds__(256) void proj_kernel(
    const float* __restrict__ x1, const float* __restrict__ x2,
    const float* __restrict__ Wqk1, const float* __restrict__ bqk1,
    const float* __restrict__ Wqk2, const float* __restrict__ bqk2,
    const float* __restrict__ Wv1,  const float* __restrict__ bv1,
    const float* __restrict__ Wv2,  const float* __restrict__ bv2,
    float* __restrict__ ws, float* __restrict__ out)
{
    const int t    = threadIdx.x;
    const int lane = t & 63;
    const int w    = t >> 6;
    const int n16  = lane & 15;
    const int c4   = lane >> 4;
    const int nt   = w & 1;
    const int mh   = w >> 1;
    const int b    = blockIdx.y;
    const int px   = blockIdx.x * 32 + nt * 16 + n16;

    const float* xsb[2];
    xsb[0] = x1 + ((size_t)b * CCH) * NPX + px;
    xsb[1] = x2 + ((size_t)b * CCH) * NPX + px;

    float xr[2][16];
    short8 bfrag[2][2];
    #pragma unroll
    for (int st = 0; st < 2; st++) {
        #pragma unroll
        for (int ch = 0; ch < 2; ch++) {
            #pragma unroll
            for (int j = 0; j < 8; j++)
                xr[st][ch * 8 + j] = xsb[st][(ch * 32 + c4 * 8 + j) * NPX];
            bfrag[st][ch] = pack8(&xr[st][ch * 8]);
        }
    }

    if (mh == 0) {
        #pragma unroll
        for (int st = 0; st < 2; st++) {
            float* outs = out + (st ? (size_t)BCN : 0);
            #pragma unroll
            for (int e = 0; e < 16; e++) {
                const int ch = (e >> 3) * 32 + c4 * 8 + (e & 7);
                outs[((size_t)b * CCH + ch) * NPX + px] = xr[st][e];
            }
        }
    }

    float4t acc[5];
    #pragma unroll
    for (int mt = 0; mt < 5; mt++) { acc[mt][0]=0.f; acc[mt][1]=0.f; acc[mt][2]=0.f; acc[mt][3]=0.f; }

    #pragma unroll
    for (int mt = 0; mt < 5; mt++) {
        const int mi  = mh * 5 + mt;
        const int isqk = (mi < 2);
        const int st  = isqk ? (mi & 1) : (mi >= 6);
        const float* Wb;
        int rowbase;
        if (isqk) { Wb = (mi == 0) ? Wqk1 : Wqk2; rowbase = 0; }
        else      { Wb = (mi >= 6) ? Wv2 : Wv1; rowbase = (mi - (mi >= 6 ? 6 : 2)) * 16; }
        const float* wrow = Wb + (size_t)(rowbase + n16) * 64 + c4 * 8;

        const short8 bf0 = st ? bfrag[1][0] : bfrag[0][0];
        const short8 bf1 = st ? bfrag[1][1] : bfrag[0][1];

        #pragma unroll
        for (int ch = 0; ch < 2; ch++) {
            float fa[8];
            const float4 a0 = *(const float4*)(wrow + ch * 32);
            const float4 a1 = *(const float4*)(wrow + ch * 32 + 4);
            fa[0] = a0.x; fa[1] = a0.y; fa[2] = a0.z; fa[3] = a0.w;
            fa[4] = a1.x; fa[5] = a1.y; fa[6] = a1.z; fa[7] = a1.w;
            acc[mt] = __builtin_amdgcn_mfma_f32_16x16x32_bf16(
                pack8(fa), ch ? bf1 : bf0, acc[mt], 0, 0, 0);
        }
    }

    #pragma unroll
    for (int mt = 0; mt < 5; mt++) {
        const int mi = mh * 5 + mt;
        if (mi < 2) {                       // qk tile (wave-uniform branch)
            const int st = mi & 1;
            const float* bqk = st ? bqk2 : bqk1;
            unsigned short* qb = (unsigned short*)(ws + (st ? WS_QB2 : WS_QB1));
            unsigned short* kb = (unsigned short*)(ws + (st ? WS_KB2 : WS_KB1));
            const size_t rbase = (size_t)(b * NPX + px) * 16;
            #pragma unroll
            for (int r = 0; r < 4; r++) {
                const int oc = c4 * 4 + r;
                const float val = acc[mt][r] + bqk[oc];
                if (oc < 8)
                    qb[rbase + oc] = bf16r(val * LOG2E);
                else
                    kb[rbase + (oc - 8)] = bf16r(val);
            }
            ushort8t zq, zk;
            #pragma unroll
            for (int e = 0; e < 8; e++) { zq[e] = 0; zk[e] = 0; }
            zk[0] = 0x3F80; zk[1] = 0x3F80;   // kb slots 8,9 = bf16(1.0)
            if (c4 == 0) *(ushort8t*)(qb + rbase + 8) = zq;
            if (c4 == 2) *(ushort8t*)(kb + rbase + 8) = zk;
        } else {                            // v tile
            const int st = (mi >= 6);
            const int vt_ = mi - (st ? 6 : 2);
            const float* bv = st ? bv2 : bv1;
            unsigned short* v = (unsigned short*)(ws + (st ? WS_V2 : WS_V1));
            #pragma unroll
            for (int r = 0; r < 4; r++) {
                const int oc = vt_ * 16 + c4 * 4 + r;
                const float val = acc[mt][r] + bv[oc];
                v[((size_t)b * CCH + oc) * NPX + px] = bf16r(val);
            }
        }
    }
}

// ---------------------------------------------------------------------------
// Kernel 2: FULL softmax denominators in ONE pass. grid (72 ig, 16 ab) =
// 1152 blocks; block owns 32 i-rows; its 4 waves are j-quarters (576 j each,
// 18 serial 32-j chunks, 1-deep kfrag prefetch, barrier-free loop).
// mfma(kf, qf): lane accumulates per-lane partial D_i over its j-rows;
// shfl_xor(32) folds the hs halves; 4-way LDS combine -> m = -log2(D) ->
// qb slots 8/9 (hi/lo bf16) directly. No pd, no fences. s_setprio around
// the MFMA (T5; independent waves). [R11-verified verbatim]
// ---------------------------------------------------------------------------
__global__ __launch_bounds__(256) void stats_kernel(float* __restrict__ ws)
{
    const int t  = threadIdx.x;
    const int w  = t >> 6;          // j-quarter 0..3
    const int n  = t & 31;
    const int h  = (t & 63) >> 5;
    const int ig = blockIdx.x;      // 0..71 (32-i group)
    const int ab = blockIdx.y;      // a*8+b
    const int b  = ab & 7;
    const int a  = ab >> 3;

    unsigned short* qbw = (unsigned short*)(ws + (a ? WS_QB2 : WS_QB1));
    const unsigned short* qb = qbw;
    const unsigned short* kb = (const unsigned short*)(ws + (a ? WS_KB2 : WS_KB1));

    __shared__ float red[4][32];

    // fixed B-operand: q rows i = ig*32 + n, k-octet h (slots 8..15 = 0)
    const short8 qf = *(const short8*)(qb + (size_t)(b * NPX + ig * 32 + n) * 16 + h * 8);

    // streamed A-operand: kb rows j = w*576 + jc*32 + n, k-octet h
    const unsigned short* kp = kb + (size_t)(b * NPX + w * 576 + n) * 16 + h * 8;
    short8 kf = *(const short8*)kp;

    float ssum = 0.f;
    for (int jc = 0; jc < 18; jc++) {
        kp += 512;                  // next 32-j chunk (32 rows x 16 shorts)
        short8 kn = kf;
        if (jc + 1 < 18) kn = *(const short8*)kp;
        float16t acc = {};
        __builtin_amdgcn_s_setprio(1);
        acc = __builtin_amdgcn_mfma_f32_32x32x16_bf16(kf, qf, acc, 0, 0, 0);
        __builtin_amdgcn_s_setprio(0);
        float s0 = 0.f, s1 = 0.f, s2 = 0.f, s3 = 0.f;
        #pragma unroll
        for (int r = 0; r < 4; r++) {
            s0 += fexp2(acc[4 * r + 0]);
            s1 += fexp2(acc[4 * r + 1]);
            s2 += fexp2(acc[4 * r + 2]);
            s3 += fexp2(acc[4 * r + 3]);
        }
        ssum += (s0 + s1) + (s2 + s3);
        kf = kn;
    }
    ssum += __shfl_xor(ssum, 32);   // fold hs halves (16 j-rows each)
    if (h == 0) red[w][n] = ssum;   // per-wave partial over its 576 j
    __syncthreads();

    if (t < 32) {
        const float d = (red[0][t] + red[1][t]) + (red[2][t] + red[3][t]);
        const float m = -__log2f(d);
        const unsigned short mhi = bf16r(m);
        __hip_bfloat16 hb; *(unsigned short*)&hb = mhi;
        const unsigned short mlo = bf16r(m - __bfloat162float(hb));
        const size_t rbase = (size_t)(b * NPX + ig * 32 + t) * 16;
        qbw[rbase + 8] = mhi;
        qbw[rbase + 9] = mlo;
    }
}

// ---------------------------------------------------------------------------
// Kernel 3 (out): R11 body with ONE delta: ZERO loop barriers via
// WAVE-PRIVATE V staging. Each wave stages its own 64c x 32i V slice (4 KB)
// into its own LDS region vt[w] (single-buffered; intra-wave ds_write ->
// ds_read is ordered by lgkmcnt, DS ops per wave process in order). The 4
// waves run the full 18 iterations fully independently -- no lockstep.
// Same global addresses / same values as R11's cooperative staging (V-direct
// to registers failed twice R4/R7 -- this keeps the LDS round trip).
// Row stride 36 shorts -> 2-way bank aliasing (free, m136). LDS 18432 B
// (same as R11); epilogue (comb reuse + 2 atomics/elem, R9-proven optimum)
// unchanged, with its barriers intact. 2-way i-split: z = o*2 + g, grid
// (36, 8, 4) = 1152 blocks. setprio kept (R11 win).
// ---------------------------------------------------------------------------
__global__ __launch_bounds__(256) void out_kernel(
    const float* __restrict__ gamma, const float* __restrict__ beta,
    const float* __restrict__ ws, float* __restrict__ out)
{
    const int t  = threadIdx.x;
    const int jt = blockIdx.x;      // 0..35
    const int b  = blockIdx.y;
    const int z  = blockIdx.z;      // o*2 + g
    const int o  = z >> 1;
    const int g  = z & 1;           // i-half (1152 i)

    const int a = o ? 0 : 1;        // attn used: o1<-attn2, o2<-attn1
    const unsigned short* qb = (const unsigned short*)(ws + (a ? WS_QB2 : WS_QB1));
    const unsigned short* kb = (const unsigned short*)(ws + (a ? WS_KB2 : WS_KB1));
    const unsigned short* v  = (const unsigned short*)(ws + (o ? WS_V2 : WS_V1));
    const float  scale = o ? beta[0] : gamma[0];

    __shared__ unsigned short vt[4][64][36];   // per-wave V slice, 18432 B

    const int lane = t & 63;
    const int w    = t >> 6;
    const int n    = lane & 31;
    const int h    = lane >> 5;
    const int jh   = w & 1;         // j-strip within block
    const int ih   = w >> 1;        // i-half within each 64-i chunk

    const int j0 = jt * 64 + jh * 32;

    // kfrag: lane n -> j = j0+n, k-octet h (c 0..7 | slots 8/9=1.0 pad)
    const short8 kfrag = *(const short8*)(kb + (size_t)(b * NPX + j0 + n) * 16 + h * 8);

    // wave's i-window base: g*1152 + ih*32, advancing 64/iter (18 iters)
    const int ibase = g * 1152 + ih * 32;

    // wave-private staging: 4 x 16B segments/lane cover [64 c][32 i].
    // id = s*64+lane: c = id>>2, off = (id&3)*8. Same global addresses as
    // R11's cooperative staging, re-partitioned per wave.
    const int id0 = lane,        c_0 = id0 >> 2, o_0 = (id0 & 3) * 8;
    const int id1 = 64  + lane,  c_1 = id1 >> 2, o_1 = (id1 & 3) * 8;
    const int id2 = 128 + lane,  c_2 = id2 >> 2, o_2 = (id2 & 3) * 8;
    const int id3 = 192 + lane,  c_3 = id3 >> 2, o_3 = (id3 & 3) * 8;
    const unsigned short* s0p = v + ((size_t)b * CCH + c_0) * NPX + ibase + o_0;
    const unsigned short* s1p = v + ((size_t)b * CCH + c_1) * NPX + ibase + o_1;
    const unsigned short* s2p = v + ((size_t)b * CCH + c_2) * NPX + ibase + o_2;
    const unsigned short* s3p = v + ((size_t)b * CCH + c_3) * NPX + ibase + o_3;
    unsigned short* d0 = &vt[w][c_0][o_0];
    unsigned short* d1 = &vt[w][c_1][o_1];
    unsigned short* d2 = &vt[w][c_2][o_2];
    unsigned short* d3 = &vt[w][c_3][o_3];

    const unsigned short* qp = qb + (size_t)(b * NPX + ibase + n) * 16 + h * 8;

    // prologue: prefetch chunk-0 V (regs) and q
    float4 vc0 = *(const float4*)s0p;
    float4 vc1 = *(const float4*)s1p;
    float4 vc2 = *(const float4*)s2p;
    float4 vc3 = *(const float4*)s3p;
    short8 qf = *(const short8*)qp;

    float16t oacc0 = {}, oacc1 = {};    // c 0..31 / c 32..63, j = j0+n (partial over ih)

    for (int it = 0; it < 18; it++) {
        // issue next chunk's global loads (1-deep prefetch)
        s0p += 64; s1p += 64; s2p += 64; s3p += 64; qp += 64 * 16;
        float4 vn0, vn1, vn2, vn3;
        short8 qn = qf;
        if (it + 1 < 18) {
            vn0 = *(const float4*)s0p;
            vn1 = *(const float4*)s1p;
            vn2 = *(const float4*)s2p;
            vn3 = *(const float4*)s3p;
            qn  = *(const short8*)qp;
        }

        // stage current chunk into this wave's private LDS slice
        // (prior iter's ds_reads are ordered before these writes per-wave)
        *(float4*)d0 = vc0;
        *(float4*)d1 = vc1;
        *(float4*)d2 = vc2;
        *(float4*)d3 = vc3;

        // S for this wave's 32 j over its 32-i window (fold included)
        // -- pure VALU/MFMA, covers the ds_write latency
        float16t sc = {};
        __builtin_amdgcn_s_setprio(1);
        sc = __builtin_amdgcn_mfma_f32_32x32x16_bf16(qf, kfrag, sc, 0, 0, 0);
        __builtin_amdgcn_s_setprio(0);

        // P -> bf16 B-fragments in-register
        short8 bf[2];
        build_bfrag(sc, bf);        // k-chunks kk=0,1 within the 32-i window

        // PV: 64 c x 32 j over this wave's 32 i (reads own slice; lgkmcnt
        // ordering vs the writes above is compiler-enforced, no barrier)
        {
            const short8 a0 = *(const short8*)&vt[w][n][h * 8];
            const short8 a1 = *(const short8*)&vt[w][32 + n][h * 8];
            __builtin_amdgcn_s_setprio(1);
            oacc0 = __builtin_amdgcn_mfma_f32_32x32x16_bf16(a0, bf[0], oacc0, 0, 0, 0);
            oacc1 = __builtin_amdgcn_mfma_f32_32x32x16_bf16(a1, bf[0], oacc1, 0, 0, 0);
            __builtin_amdgcn_s_setprio(0);
            const short8 a2 = *(const short8*)&vt[w][n][16 + h * 8];
            const short8 a3 = *(const short8*)&vt[w][32 + n][16 + h * 8];
            __builtin_amdgcn_s_setprio(1);
            oacc0 = __builtin_amdgcn_mfma_f32_32x32x16_bf16(a2, bf[1], oacc0, 0, 0, 0);
            oacc1 = __builtin_amdgcn_mfma_f32_32x32x16_bf16(a3, bf[1], oacc1, 0, 0, 0);
            __builtin_amdgcn_s_setprio(0);
        }

        vc0 = vn0; vc1 = vn1; vc2 = vn2; vc3 = vn3;
        qf = qn;
    }

    // -------- epilogue: combine ih pair via LDS (reuses vt), then atomics --
    __syncthreads();                // all waves done with their vt slices
    float* comb = (float*)&vt[0][0][0];         // 2 x 2304 floats (18432 B)
    float* cb = comb + (size_t)jh * 2304 + (size_t)lane * 36;
    if (ih == 1) {
        *(float4*)(cb +  0) = *((const float4*)&oacc0 + 0);
        *(float4*)(cb +  4) = *((const float4*)&oacc0 + 1);
        *(float4*)(cb +  8) = *((const float4*)&oacc0 + 2);
        *(float4*)(cb + 12) = *((const float4*)&oacc0 + 3);
        *(float4*)(cb + 16) = *((const float4*)&oacc1 + 0);
        *(float4*)(cb + 20) = *((const float4*)&oacc1 + 1);
        *(float4*)(cb + 24) = *((const float4*)&oacc1 + 2);
        *(float4*)(cb + 28) = *((const float4*)&oacc1 + 3);
    }
    __syncthreads();
    if (ih == 0) {
        #pragma unroll
        for (int q = 0; q < 4; q++) {
            const float4 p0 = *(const float4*)(cb + q * 4);
            const float4 p1 = *(const float4*)(cb + 16 + q * 4);
            oacc0[4*q+0] += p0.x; oacc0[4*q+1] += p0.y; oacc0[4*q+2] += p0.z; oacc0[4*q+3] += p0.w;
            oacc1[4*q+0] += p1.x; oacc1[4*q+1] += p1.y; oacc1[4*q+2] += p1.z; oacc1[4*q+3] += p1.w;
        }
        // out += scale*acc (residual already in out). 32-bit indexing.
        float* outp = out + (o ? BCN : 0) + (b * CCH) * NPX + j0 + n;
        #pragma unroll
        for (int r = 0; r < 16; r++) {
            const int row = (r & 3) + 8 * (r >> 2) + 4 * h;
            atomicAdd(outp + row * NPX, oacc0[r] * scale);
            atomicAdd(outp + (32 + row) * NPX, oacc1[r] * scale);
        }
    }
}

// ---------------------------------------------------------------------------
extern "C" void kernel_launch(void* const* d_in, const int* in_sizes, int n_in,
                              void* d_out, int out_size, void* d_ws, size_t ws_size,
                              hipStream_t stream)
{
    const float* x1   = (const float*)d_in[0];
    const float* x2   = (const float*)d_in[1];
    const float* Wqk1 = (const float*)d_in[2];
    const float* bqk1 = (const float*)d_in[3];
    const float* Wqk2 = (const float*)d_in[4];
    const float* bqk2 = (const float*)d_in[5];
    const float* Wv1  = (const float*)d_in[6];
    const float* bv1  = (const float*)d_in[7];
    const float* Wv2  = (const float*)d_in[8];
    const float* bv2  = (const float*)d_in[9];
    const float* gamma = (const float*)d_in[10];
    const float* beta  = (const float*)d_in[11];
    float* out = (float*)d_out;
    float* ws  = (float*)d_ws;

    proj_kernel<<<dim3(72, 8), 256, 0, stream>>>(
        x1, x2, Wqk1, bqk1, Wqk2, bqk2, Wv1, bv1, Wv2, bv2, ws, out);
    stats_kernel<<<dim3(72, 16), 256, 0, stream>>>(ws);
    out_kernel<<<dim3(36, 8, 4), 256, 0, stream>>>(gamma, beta, ws, out);
}

// Round 13
// 134.684 us; speedup vs baseline: 1.1635x; 1.1635x over previous
//
#include <hip/hip_runtime.h>
#include <hip/hip_bf16.h>

// Problem constants
#define NB   8
#define CCH  64
#define CR8  8
#define NPX  2304           // 48*48
#define BCN  (NB*CCH*NPX)   // 1179648
#define LOG2E 1.4426950408889634f

typedef short  short8   __attribute__((ext_vector_type(8)));
typedef unsigned short ushort8t __attribute__((ext_vector_type(8)));
typedef float  float4t  __attribute__((ext_vector_type(4)));
typedef float  float16t __attribute__((ext_vector_type(16)));

// native v_exp_f32 (1 inst; ~1 ulp; valid for our |x| < ~50 range).
static __device__ __forceinline__ float fexp2(float x) {
    return __builtin_amdgcn_exp2f(x);
}
// round-half-up bf16 from f32: (u + 0x8000) >> 16  (<=1 ulp vs RNE)
static __device__ __forceinline__ unsigned short bf16r(float f) {
    return (unsigned short)((__float_as_uint(f) + 0x8000u) >> 16);
}
// pack two f32 -> two bf16 in one dword: [hi16(hi) : hi16(lo)], 3 VALU inst
static __device__ __forceinline__ unsigned int pack_bf16(float lo, float hi) {
    const unsigned int ul = __float_as_uint(lo) + 0x8000u;
    const unsigned int uh = __float_as_uint(hi) + 0x8000u;
    return __builtin_amdgcn_perm(uh, ul, 0x07060302u);
}
// 8 floats -> short8 bf16 fragment (4 perms)
static __device__ __forceinline__ short8 pack8(const float* f) {
    union { unsigned int u[4]; short8 s; } r;
    #pragma unroll
    for (int j = 0; j < 4; j++) r.u[j] = pack_bf16(f[2*j], f[2*j+1]);
    return r.s;
}

// Build the two PV B-fragments (K=16 chunks kp=0,1) for one 32x32 S-MFMA
// output, entirely in registers. S output: lane (j=l&31, hs=l>>5) reg r holds
// S[row=(r&3)+8*(r>>2)+4*hs][j]. After exp2+pack, d[q][m] holds rows
// (8q+4hs+2m, +2m+1). B-frag for chunk kp needs lane (j,h) to hold rows
// 16kp+8h+0..7 at k-octet h. v_permlane32_swap_b32 (dst.row1 <-> src.row0):
//   x' = {x.lo, y.lo}, y' = {x.hi, y.hi}
// so swap(d[2kp][m], d[2kp+1][m]) yields frag words (m, 2+m) for ALL lanes.
// [verified R1/R2/R5/R6/R8/R9/R11]
static __device__ __forceinline__ void build_bfrag(const float16t sc, short8* bf) {
    unsigned int d[4][2];
    #pragma unroll
    for (int q = 0; q < 4; q++) {
        #pragma unroll
        for (int m = 0; m < 2; m++)
            d[q][m] = pack_bf16(fexp2(sc[4*q + 2*m]), fexp2(sc[4*q + 2*m + 1]));
    }
    #pragma unroll
    for (int kp = 0; kp < 2; kp++) {
        union { unsigned int u[4]; short8 s; } r;
        #pragma unroll
        for (int m = 0; m < 2; m++) {
            unsigned int x = d[2*kp][m];
            unsigned int y = d[2*kp + 1][m];
            asm("v_permlane32_swap_b32 %0, %1" : "+v"(x), "+v"(y));
            r.u[m]     = x;
            r.u[2 + m] = y;
        }
        bf[kp] = r.s;
    }
}

// Workspace layout (float offsets)
// qb/kb: bf16 [b][i][16] rows. qb: c 0..7 = q*log2e, slots 8/9 get
// -log2(D_i) hi/lo AFTER stats; kb: c 0..7 = k, slots 8/9 = 1.0.
// The S-MFMA in out_kernel then yields log2(P_normalized) directly.
#define WS_QB1 0
#define WS_KB1 (WS_QB1 + 147456)
#define WS_QB2 (WS_KB1 + 147456)
#define WS_KB2 (WS_QB2 + 147456)
#define WS_V1  (WS_KB2 + 147456)        // bf16 [b][c][i], unscaled
#define WS_V2  (WS_V1 + BCN/2)

// ---------------------------------------------------------------------------
// Kernel 1: projections as MFMA GEMM. M=160 rows (qk1,qk2,v1,v2), N=px, K=64.
// grid (72 pxtiles of 32, 8 b), block 256 = 4 independent waves, NO LDS,
// NO barriers. Also writes out = x residual-init. kb pad slots 8,9 = 1.0.
// [R2-verified verbatim]
// ---------------------------------------------------------------------------
__global__ __launch_bounds__(256) void proj_kernel(
    const float* __restrict__ x1, const float* __restrict__ x2,
    const float* __restrict__ Wqk1, const float* __restrict__ bqk1,
    const float* __restrict__ Wqk2, const float* __restrict__ bqk2,
    const float* __restrict__ Wv1,  const float* __restrict__ bv1,
    const float* __restrict__ Wv2,  const float* __restrict__ bv2,
    float* __restrict__ ws, float* __restrict__ out)
{
    const int t    = threadIdx.x;
    const int lane = t & 63;
    const int w    = t >> 6;
    const int n16  = lane & 15;
    const int c4   = lane >> 4;
    const int nt   = w & 1;
    const int mh   = w >> 1;
    const int b    = blockIdx.y;
    const int px   = blockIdx.x * 32 + nt * 16 + n16;

    const float* xsb[2];
    xsb[0] = x1 + ((size_t)b * CCH) * NPX + px;
    xsb[1] = x2 + ((size_t)b * CCH) * NPX + px;

    float xr[2][16];
    short8 bfrag[2][2];
    #pragma unroll
    for (int st = 0; st < 2; st++) {
        #pragma unroll
        for (int ch = 0; ch < 2; ch++) {
            #pragma unroll
            for (int j = 0; j < 8; j++)
                xr[st][ch * 8 + j] = xsb[st][(ch * 32 + c4 * 8 + j) * NPX];
            bfrag[st][ch] = pack8(&xr[st][ch * 8]);
        }
    }

    if (mh == 0) {
        #pragma unroll
        for (int st = 0; st < 2; st++) {
            float* outs = out + (st ? (size_t)BCN : 0);
            #pragma unroll
            for (int e = 0; e < 16; e++) {
                const int ch = (e >> 3) * 32 + c4 * 8 + (e & 7);
                outs[((size_t)b * CCH + ch) * NPX + px] = xr[st][e];
            }
        }
    }

    float4t acc[5];
    #pragma unroll
    for (int mt = 0; mt < 5; mt++) { acc[mt][0]=0.f; acc[mt][1]=0.f; acc[mt][2]=0.f; acc[mt][3]=0.f; }

    #pragma unroll
    for (int mt = 0; mt < 5; mt++) {
        const int mi  = mh * 5 + mt;
        const int isqk = (mi < 2);
        const int st  = isqk ? (mi & 1) : (mi >= 6);
        const float* Wb;
        int rowbase;
        if (isqk) { Wb = (mi == 0) ? Wqk1 : Wqk2; rowbase = 0; }
        else      { Wb = (mi >= 6) ? Wv2 : Wv1; rowbase = (mi - (mi >= 6 ? 6 : 2)) * 16; }
        const float* wrow = Wb + (size_t)(rowbase + n16) * 64 + c4 * 8;

        const short8 bf0 = st ? bfrag[1][0] : bfrag[0][0];
        const short8 bf1 = st ? bfrag[1][1] : bfrag[0][1];

        #pragma unroll
        for (int ch = 0; ch < 2; ch++) {
            float fa[8];
            const float4 a0 = *(const float4*)(wrow + ch * 32);
            const float4 a1 = *(const float4*)(wrow + ch * 32 + 4);
            fa[0] = a0.x; fa[1] = a0.y; fa[2] = a0.z; fa[3] = a0.w;
            fa[4] = a1.x; fa[5] = a1.y; fa[6] = a1.z; fa[7] = a1.w;
            acc[mt] = __builtin_amdgcn_mfma_f32_16x16x32_bf16(
                pack8(fa), ch ? bf1 : bf0, acc[mt], 0, 0, 0);
        }
    }

    #pragma unroll
    for (int mt = 0; mt < 5; mt++) {
        const int mi = mh * 5 + mt;
        if (mi < 2) {                       // qk tile (wave-uniform branch)
            const int st = mi & 1;
            const float* bqk = st ? bqk2 : bqk1;
            unsigned short* qb = (unsigned short*)(ws + (st ? WS_QB2 : WS_QB1));
            unsigned short* kb = (unsigned short*)(ws + (st ? WS_KB2 : WS_KB1));
            const size_t rbase = (size_t)(b * NPX + px) * 16;
            #pragma unroll
            for (int r = 0; r < 4; r++) {
                const int oc = c4 * 4 + r;
                const float val = acc[mt][r] + bqk[oc];
                if (oc < 8)
                    qb[rbase + oc] = bf16r(val * LOG2E);
                else
                    kb[rbase + (oc - 8)] = bf16r(val);
            }
            ushort8t zq, zk;
            #pragma unroll
            for (int e = 0; e < 8; e++) { zq[e] = 0; zk[e] = 0; }
            zk[0] = 0x3F80; zk[1] = 0x3F80;   // kb slots 8,9 = bf16(1.0)
            if (c4 == 0) *(ushort8t*)(qb + rbase + 8) = zq;
            if (c4 == 2) *(ushort8t*)(kb + rbase + 8) = zk;
        } else {                            // v tile
            const int st = (mi >= 6);
            const int vt_ = mi - (st ? 6 : 2);
            const float* bv = st ? bv2 : bv1;
            unsigned short* v = (unsigned short*)(ws + (st ? WS_V2 : WS_V1));
            #pragma unroll
            for (int r = 0; r < 4; r++) {
                const int oc = vt_ * 16 + c4 * 4 + r;
                const float val = acc[mt][r] + bv[oc];
                v[((size_t)b * CCH + oc) * NPX + px] = bf16r(val);
            }
        }
    }
}

// ---------------------------------------------------------------------------
// Kernel 2: FULL softmax denominators in ONE pass. grid (72 ig, 16 ab) =
// 1152 blocks; block owns 32 i-rows; its 4 waves are j-quarters (576 j each,
// 18 serial 32-j chunks, 1-deep kfrag prefetch, barrier-free loop).
// mfma(kf, qf): lane accumulates per-lane partial D_i over its j-rows;
// shfl_xor(32) folds the hs halves; 4-way LDS combine -> m = -log2(D) ->
// qb slots 8/9 (hi/lo bf16) directly. No pd, no fences. s_setprio around
// the MFMA (T5; independent waves). [R11-verified verbatim]
// ---------------------------------------------------------------------------
__global__ __launch_bounds__(256) void stats_kernel(float* __restrict__ ws)
{
    const int t  = threadIdx.x;
    const int w  = t >> 6;          // j-quarter 0..3
    const int n  = t & 31;
    const int h  = (t & 63) >> 5;
    const int ig = blockIdx.x;      // 0..71 (32-i group)
    const int ab = blockIdx.y;      // a*8+b
    const int b  = ab & 7;
    const int a  = ab >> 3;

    unsigned short* qbw = (unsigned short*)(ws + (a ? WS_QB2 : WS_QB1));
    const unsigned short* qb = qbw;
    const unsigned short* kb = (const unsigned short*)(ws + (a ? WS_KB2 : WS_KB1));

    __shared__ float red[4][32];

    // fixed B-operand: q rows i = ig*32 + n, k-octet h (slots 8..15 = 0)
    const short8 qf = *(const short8*)(qb + (size_t)(b * NPX + ig * 32 + n) * 16 + h * 8);

    // streamed A-operand: kb rows j = w*576 + jc*32 + n, k-octet h
    const unsigned short* kp = kb + (size_t)(b * NPX + w * 576 + n) * 16 + h * 8;
    short8 kf = *(const short8*)kp;

    float ssum = 0.f;
    for (int jc = 0; jc < 18; jc++) {
        kp += 512;                  // next 32-j chunk (32 rows x 16 shorts)
        short8 kn = kf;
        if (jc + 1 < 18) kn = *(const short8*)kp;
        float16t acc = {};
        __builtin_amdgcn_s_setprio(1);
        acc = __builtin_amdgcn_mfma_f32_32x32x16_bf16(kf, qf, acc, 0, 0, 0);
        __builtin_amdgcn_s_setprio(0);
        float s0 = 0.f, s1 = 0.f, s2 = 0.f, s3 = 0.f;
        #pragma unroll
        for (int r = 0; r < 4; r++) {
            s0 += fexp2(acc[4 * r + 0]);
            s1 += fexp2(acc[4 * r + 1]);
            s2 += fexp2(acc[4 * r + 2]);
            s3 += fexp2(acc[4 * r + 3]);
        }
        ssum += (s0 + s1) + (s2 + s3);
        kf = kn;
    }
    ssum += __shfl_xor(ssum, 32);   // fold hs halves (16 j-rows each)
    if (h == 0) red[w][n] = ssum;   // per-wave partial over its 576 j
    __syncthreads();

    if (t < 32) {
        const float d = (red[0][t] + red[1][t]) + (red[2][t] + red[3][t]);
        const float m = -__log2f(d);
        const unsigned short mhi = bf16r(m);
        __hip_bfloat16 hb; *(unsigned short*)&hb = mhi;
        const unsigned short mlo = bf16r(m - __bfloat162float(hb));
        const size_t rbase = (size_t)(b * NPX + ig * 32 + t) * 16;
        qbw[rbase + 8] = mhi;
        qbw[rbase + 9] = mlo;
    }
}

// ---------------------------------------------------------------------------
// Kernel 3 (out): R9-verified body + setprio (R11, 136.96 us session best).
// 2-way i-split: z = o*2 + g (g = 1152-i half), 18 loop iterations, grid
// (36, 8, 4) = 1152 blocks all co-resident. Cooperative double-buffered V
// staging (1 barrier/iter -- measured cheaper than every alternative:
// R10 c-split -3.9us, R12 wave-private -20us, V-direct broken R4/R7).
// 2 atomicAdds per output element: the measured optimum of the
// atomic/duplication trade (R9 +5.3us over 4-way).
// ---------------------------------------------------------------------------
__global__ __launch_bounds__(256) void out_kernel(
    const float* __restrict__ gamma, const float* __restrict__ beta,
    const float* __restrict__ ws, float* __restrict__ out)
{
    const int t  = threadIdx.x;
    const int jt = blockIdx.x;      // 0..35
    const int b  = blockIdx.y;
    const int z  = blockIdx.z;      // o*2 + g
    const int o  = z >> 1;
    const int g  = z & 1;           // i-half (1152 i)

    const int a = o ? 0 : 1;        // attn used: o1<-attn2, o2<-attn1
    const unsigned short* qb = (const unsigned short*)(ws + (a ? WS_QB2 : WS_QB1));
    const unsigned short* kb = (const unsigned short*)(ws + (a ? WS_KB2 : WS_KB1));
    const unsigned short* v  = (const unsigned short*)(ws + (o ? WS_V2 : WS_V1));
    const float  scale = o ? beta[0] : gamma[0];

    __shared__ unsigned short vt[2][64][72];   // v[c][i], double-buffered

    const int lane = t & 63;
    const int w    = t >> 6;
    const int n    = lane & 31;
    const int h    = lane >> 5;
    const int jh   = w & 1;         // j-strip within block
    const int ih   = w >> 1;        // i-half within 64-i chunk

    const int j0 = jt * 64 + jh * 32;

    // kfrag: lane n -> j = j0+n, k-octet h (c 0..7 | slots 8/9=1.0 pad)
    const short8 kfrag = *(const short8*)(kb + (size_t)(b * NPX + j0 + n) * 16 + h * 8);

    // vt staging indices (2 x 16B segments per thread, coalesced)
    const int c0 = t >> 3, s80 = (t & 7) * 8;
    const int c1 = (t + 256) >> 3, s81 = ((t + 256) & 7) * 8;

    const int ibase = g * 1152;
    const unsigned short* vp0 = v + ((size_t)b * CCH + c0) * NPX + ibase + s80;
    const unsigned short* vp1 = v + ((size_t)b * CCH + c1) * NPX + ibase + s81;
    const unsigned short* qp  = qb + (size_t)(b * NPX + ibase + ih * 32 + n) * 16 + h * 8;

    // prologue: stage chunk 0 into vt[0], prefetch chunk-0 q
    {
        const float4 va = *(const float4*)vp0;
        const float4 vb = *(const float4*)vp1;
        *(float4*)&vt[0][c0][s80] = va;
        *(float4*)&vt[0][c1][s81] = vb;
    }
    short8 qf = *(const short8*)qp;

    float16t oacc0 = {}, oacc1 = {};    // c 0..31 / c 32..63, j = j0+n (partial over ih)
    int cur = 0;

    for (int it = 0; it < 18; it++) {
        // issue next chunk's loads before the barrier
        vp0 += 64; vp1 += 64; qp += 64 * 16;
        float4 vn0, vn1;
        short8 qn = qf;
        if (it + 1 < 18) {
            vn0 = *(const float4*)vp0;
            vn1 = *(const float4*)vp1;
            qn  = *(const short8*)qp;
        }

        __syncthreads();    // vt[cur] writes visible; prior reads of vt[cur^1] done

        // S for this wave's 32 j over its 32-i half (fold included)
        float16t sc = {};
        __builtin_amdgcn_s_setprio(1);
        sc = __builtin_amdgcn_mfma_f32_32x32x16_bf16(qf, kfrag, sc, 0, 0, 0);
        __builtin_amdgcn_s_setprio(0);

        // P -> bf16 B-fragments in-register (no vt dependency)
        short8 bf[2];
        build_bfrag(sc, bf);        // i-offsets ih*32 + {0..15, 16..31}

        // PV: 64 c x 32 j over this wave's 32 i
        {
            const short8 a0 = *(const short8*)&vt[cur][n][ih * 32 + 0 * 16 + h * 8];
            const short8 a1 = *(const short8*)&vt[cur][32 + n][ih * 32 + 0 * 16 + h * 8];
            __builtin_amdgcn_s_setprio(1);
            oacc0 = __builtin_amdgcn_mfma_f32_32x32x16_bf16(a0, bf[0], oacc0, 0, 0, 0);
            oacc1 = __builtin_amdgcn_mfma_f32_32x32x16_bf16(a1, bf[0], oacc1, 0, 0, 0);
            __builtin_amdgcn_s_setprio(0);
            const short8 a2 = *(const short8*)&vt[cur][n][ih * 32 + 1 * 16 + h * 8];
            const short8 a3 = *(const short8*)&vt[cur][32 + n][ih * 32 + 1 * 16 + h * 8];
            __builtin_amdgcn_s_setprio(1);
            oacc0 = __builtin_amdgcn_mfma_f32_32x32x16_bf16(a2, bf[1], oacc0, 0, 0, 0);
            oacc1 = __builtin_amdgcn_mfma_f32_32x32x16_bf16(a3, bf[1], oacc1, 0, 0, 0);
            __builtin_amdgcn_s_setprio(0);
        }

        // write next chunk into the other buffer (no race: different buffer;
        // next iteration's barrier publishes it before any read)
        if (it + 1 < 18) {
            *(float4*)&vt[cur ^ 1][c0][s80] = vn0;
            *(float4*)&vt[cur ^ 1][c1][s81] = vn1;
        }

        qf = qn;
        cur ^= 1;
    }

    // -------- epilogue: combine ih pair via LDS (reuses vt), then atomics --
    __syncthreads();                // all PV reads of vt done
    float* comb = (float*)&vt[0][0][0];         // 2 x 2304 floats (stride 36/lane)
    float* cb = comb + (size_t)jh * 2304 + (size_t)lane * 36;
    if (ih == 1) {
        *(float4*)(cb +  0) = *((const float4*)&oacc0 + 0);
        *(float4*)(cb +  4) = *((const float4*)&oacc0 + 1);
        *(float4*)(cb +  8) = *((const float4*)&oacc0 + 2);
        *(float4*)(cb + 12) = *((const float4*)&oacc0 + 3);
        *(float4*)(cb + 16) = *((const float4*)&oacc1 + 0);
        *(float4*)(cb + 20) = *((const float4*)&oacc1 + 1);
        *(float4*)(cb + 24) = *((const float4*)&oacc1 + 2);
        *(float4*)(cb + 28) = *((const float4*)&oacc1 + 3);
    }
    __syncthreads();
    if (ih == 0) {
        #pragma unroll
        for (int q = 0; q < 4; q++) {
            const float4 p0 = *(const float4*)(cb + q * 4);
            const float4 p1 = *(const float4*)(cb + 16 + q * 4);
            oacc0[4*q+0] += p0.x; oacc0[4*q+1] += p0.y; oacc0[4*q+2] += p0.z; oacc0[4*q+3] += p0.w;
            oacc1[4*q+0] += p1.x; oacc1[4*q+1] += p1.y; oacc1[4*q+2] += p1.z; oacc1[4*q+3] += p1.w;
        }
        // out += scale*acc (residual already in out). 32-bit indexing.
        float* outp = out + (o ? BCN : 0) + (b * CCH) * NPX + j0 + n;
        #pragma unroll
        for (int r = 0; r < 16; r++) {
            const int row = (r & 3) + 8 * (r >> 2) + 4 * h;
            atomicAdd(outp + row * NPX, oacc0[r] * scale);
            atomicAdd(outp + (32 + row) * NPX, oacc1[r] * scale);
        }
    }
}

// ---------------------------------------------------------------------------
extern "C" void kernel_launch(void* const* d_in, const int* in_sizes, int n_in,
                              void* d_out, int out_size, void* d_ws, size_t ws_size,
                              hipStream_t stream)
{
    const float* x1   = (const float*)d_in[0];
    const float* x2   = (const float*)d_in[1];
    const float* Wqk1 = (const float*)d_in[2];
    const float* bqk1 = (const float*)d_in[3];
    const float* Wqk2 = (const float*)d_in[4];
    const float* bqk2 = (const float*)d_in[5];
    const float* Wv1  = (const float*)d_in[6];
    const float* bv1  = (const float*)d_in[7];
    const float* Wv2  = (const float*)d_in[8];
    const float* bv2  = (const float*)d_in[9];
    const float* gamma = (const float*)d_in[10];
    const float* beta  = (const float*)d_in[11];
    float* out = (float*)d_out;
    float* ws  = (float*)d_ws;

    proj_kernel<<<dim3(72, 8), 256, 0, stream>>>(
        x1, x2, Wqk1, bqk1, Wqk2, bqk2, Wv1, bv1, Wv2, bv2, ws, out);
    stats_kernel<<<dim3(72, 16), 256, 0, stream>>>(ws);
    out_kernel<<<dim3(36, 8, 4), 256, 0, stream>>>(gamma, beta, ws, out);
}